// Round 1
// baseline (179.004 us; speedup 1.0000x reference)
//
#include <hip/hip_runtime.h>
#include <hip/hip_bf16.h>
#include <math.h>

// Problem constants (B=8, N=1025, D=64 per reference setup_inputs)
#define BN 8
#define NN 1025
#define DD 64
#define T_ROWS 8192   // 8 * 1024

// ws layout (float offsets)
#define WS_QN   0         // [8192][64]
#define WS_KN   524288    // [8192][64]
#define WS_DIAG 1048576   // [8192]  (logit value: 20*dot)
#define WS_BIAS 1056768   // [8192]  (valid ? -20*log2e : -inf)
#define WS_S    1064960   // [8192]  (exp-sum accumulators)

#define C_EXP 28.85390081777927f  // 20 / ln(2)

// ---------------------------------------------------------------------------
// Prep: L2-normalize q (output[:, :-1]) and k (target[:, 1:]), compute diag
// logits, column bias (mask), and zero the s accumulators.
// One wave per row.
// ---------------------------------------------------------------------------
__global__ __launch_bounds__(256) void prep_kernel(
    const float* __restrict__ outE, const float* __restrict__ tgtE,
    const int* __restrict__ mask, float* __restrict__ ws)
{
    int wid  = threadIdx.x >> 6;
    int lane = threadIdx.x & 63;
    int t = blockIdx.x * 4 + wid;
    if (t >= T_ROWS) return;
    int b = t >> 10;
    int n = t & 1023;
    size_t qoff = ((size_t)(b * NN + n)) * DD;
    size_t koff = ((size_t)(b * NN + n + 1)) * DD;
    float qv = outE[qoff + lane];
    float kv = tgtE[koff + lane];
    float qs = qv * qv, ks = kv * kv;
    #pragma unroll
    for (int m = 32; m; m >>= 1) {
        qs += __shfl_xor(qs, m, 64);
        ks += __shfl_xor(ks, m, 64);
    }
    float qinv = 1.0f / fmaxf(sqrtf(qs), 1e-12f);
    float kinv = 1.0f / fmaxf(sqrtf(ks), 1e-12f);
    float qn  = qv * qinv;
    float knv = kv * kinv;
    ws[WS_QN + (size_t)t * DD + lane] = qn;
    ws[WS_KN + (size_t)t * DD + lane] = knv;
    float dt = qn * knv;
    #pragma unroll
    for (int m = 32; m; m >>= 1) dt += __shfl_xor(dt, m, 64);
    if (lane == 0) {
        ws[WS_DIAG + t] = 20.0f * dt;
        int v = mask[b * NN + n + 1];
        ws[WS_BIAS + t] = v ? -C_EXP : -INFINITY;
        ws[WS_S + t] = 0.0f;
    }
}

// ---------------------------------------------------------------------------
// Main: s[i] += sum_j exp(20*dot(qn_i, kn_j) - 20) * valid_j
// 128x128 block tile, 256 threads, 8x8 per thread (rows/cols strided by 16),
// full D=64 in LDS. Q tile loaded once; 8 j-tiles per block; partials via
// atomicAdd (plain addition valid because of the fixed max = 20).
// ---------------------------------------------------------------------------
#define BI 128
#define BJ 128
#define JCHUNK 8
#define LSTR 68   // LDS row stride in floats (64 + 4 pad)

__global__ __launch_bounds__(256, 2) void logits_kernel(
    const float* __restrict__ qn, const float* __restrict__ kn,
    const float* __restrict__ bias, float* __restrict__ s)
{
    __shared__ float Qs[BI][LSTR];
    __shared__ float Ks[BJ][LSTR];
    int ib = blockIdx.x >> 3;   // 64 i-tiles
    int jc = blockIdx.x & 7;    // 8 j-chunks
    int i0 = ib * BI;
    int tid = threadIdx.x;

    // Load Q tile (128 x 64 floats): 8 float4 per thread, coalesced
    #pragma unroll
    for (int r = 0; r < 8; ++r) {
        int idx = tid + 256 * r;
        int row = idx >> 4, c4 = idx & 15;
        float4 v = *(const float4*)(qn + (size_t)(i0 + row) * DD + c4 * 4);
        *(float4*)&Qs[row][c4 * 4] = v;
    }

    int ty = tid >> 4, tx = tid & 15;
    float acc_s[8];
    #pragma unroll
    for (int r = 0; r < 8; ++r) acc_s[r] = 0.f;

    for (int jt = 0; jt < JCHUNK; ++jt) {
        int j0 = jc * (BJ * JCHUNK) + jt * BJ;
        if (jt) __syncthreads();
        #pragma unroll
        for (int r = 0; r < 8; ++r) {
            int idx = tid + 256 * r;
            int row = idx >> 4, c4 = idx & 15;
            float4 v = *(const float4*)(kn + (size_t)(j0 + row) * DD + c4 * 4);
            *(float4*)&Ks[row][c4 * 4] = v;
        }
        __syncthreads();

        float dot[8][8];
        #pragma unroll
        for (int r = 0; r < 8; ++r)
            #pragma unroll
            for (int c = 0; c < 8; ++c) dot[r][c] = 0.f;

        for (int d = 0; d < 64; d += 4) {
            float4 qv[8], kv[8];
            #pragma unroll
            for (int r = 0; r < 8; ++r) qv[r] = *(const float4*)&Qs[ty + 16 * r][d];
            #pragma unroll
            for (int c = 0; c < 8; ++c) kv[c] = *(const float4*)&Ks[tx + 16 * c][d];
            #pragma unroll
            for (int r = 0; r < 8; ++r) {
                #pragma unroll
                for (int c = 0; c < 8; ++c) {
                    dot[r][c] = fmaf(qv[r].x, kv[c].x, dot[r][c]);
                    dot[r][c] = fmaf(qv[r].y, kv[c].y, dot[r][c]);
                    dot[r][c] = fmaf(qv[r].z, kv[c].z, dot[r][c]);
                    dot[r][c] = fmaf(qv[r].w, kv[c].w, dot[r][c]);
                }
            }
        }

        // exp tail with mask folded into the bias (exp2(-inf) = 0)
        #pragma unroll
        for (int c = 0; c < 8; ++c) {
            float bb = bias[j0 + tx + 16 * c];
            #pragma unroll
            for (int r = 0; r < 8; ++r)
                acc_s[r] += exp2f(fmaf(dot[r][c], C_EXP, bb));
        }
    }

    // Reduce across the 16 tx lanes sharing each row group (consecutive lanes)
    #pragma unroll
    for (int m = 1; m < 16; m <<= 1)
        #pragma unroll
        for (int r = 0; r < 8; ++r)
            acc_s[r] += __shfl_xor(acc_s[r], m, 64);

    if (tx == 0) {
        #pragma unroll
        for (int r = 0; r < 8; ++r)
            atomicAdd(&s[i0 + ty + 16 * r], acc_s[r]);
    }
}

// ---------------------------------------------------------------------------
// Final reduce: loss = -(1/V) * sum_{i valid} (diag_i - (20 + ln(s_i)))
// ---------------------------------------------------------------------------
__global__ __launch_bounds__(1024) void loss_kernel(
    const float* __restrict__ ws, float* __restrict__ out)
{
    const float* diag = ws + WS_DIAG;
    const float* bias = ws + WS_BIAS;
    const float* sарr = ws + WS_S;
    int tid = threadIdx.x;
    double num = 0.0;
    float den = 0.f;
    #pragma unroll
    for (int r = 0; r < 8; ++r) {
        int t = tid + 1024 * r;
        float bb = bias[t];
        if (bb > -1e30f) {
            float lse = 20.0f + logf(sарr[t]);
            num += (double)(diag[t] - lse);
            den += 1.f;
        }
    }
    #pragma unroll
    for (int m = 32; m; m >>= 1) {
        num += __shfl_xor(num, m, 64);
        den += __shfl_xor(den, m, 64);
    }
    __shared__ double ln_[16];
    __shared__ float ld_[16];
    int w = tid >> 6, lane = tid & 63;
    if (lane == 0) { ln_[w] = num; ld_[w] = den; }
    __syncthreads();
    if (tid == 0) {
        double tn = 0.0; float td = 0.f;
        for (int i = 0; i < 16; ++i) { tn += ln_[i]; td += ld_[i]; }
        out[0] = (float)(-tn / (double)td);
    }
}

extern "C" void kernel_launch(void* const* d_in, const int* in_sizes, int n_in,
                              void* d_out, int out_size, void* d_ws, size_t ws_size,
                              hipStream_t stream) {
    const float* outE = (const float*)d_in[0];
    const float* tgtE = (const float*)d_in[1];
    const int*   mask = (const int*)d_in[2];
    float* ws = (float*)d_ws;
    float* out = (float*)d_out;

    prep_kernel<<<T_ROWS / 4, 256, 0, stream>>>(outE, tgtE, mask, ws);
    logits_kernel<<<(T_ROWS / BI) * JCHUNK, 256, 0, stream>>>(
        ws + WS_QN, ws + WS_KN, ws + WS_BIAS, ws + WS_S);
    loss_kernel<<<1, 1024, 0, stream>>>(ws, out);
}

// Round 2
// 90.834 us; speedup vs baseline: 1.9707x; 1.9707x over previous
//
#include <hip/hip_runtime.h>
#include <hip/hip_bf16.h>
#include <math.h>

// Problem constants (B=8, N=1025, D=64 per reference setup_inputs)
#define NN 1025
#define DD 64
#define T_ROWS 8192            // 8 * 1024
#define C_EXP 28.85390081777927f      // 20 / ln(2) = 20*log2(e)
#define EXP_NEG20 2.0611536224385583e-9f  // e^-20

typedef _Float16 h8 __attribute__((ext_vector_type(8)));
typedef float f4 __attribute__((ext_vector_type(4)));

// ws layout (bytes):
//   qh   : _Float16[8192*64] @ 0         (1 MB)  = qhat * C_EXP
//   kh   : _Float16[8192*64] @ 0x100000  (1 MB)  = khat
//   diag : float[8192]       @ 0x200000  (32 KB) = 20*dot(qhat_i, khat_i)
//   scale: float[8192]       @ 0x208000  (32 KB) = valid_j ? e^-20 : 0
//   s    : float[8192]       @ 0x210000  (32 KB) = sum_j e^{logit_ij - 20}
//   red  : float[2]          @ 0x218000          = (num, den)
#define OFF_QH   0
#define OFF_KH   (1 << 20)
#define OFF_DIAG (2 << 20)

// ---------------------------------------------------------------------------
// Prep: normalize, convert to f16 (Q pre-scaled by 20*log2e), exact fp32 diag,
// multiplicative mask, zero accumulators. One wave per row.
// ---------------------------------------------------------------------------
__global__ __launch_bounds__(256) void prep_kernel(
    const float* __restrict__ outE, const float* __restrict__ tgtE,
    const int* __restrict__ mask, char* __restrict__ wsb)
{
    _Float16* qh = (_Float16*)(wsb + OFF_QH);
    _Float16* kh = (_Float16*)(wsb + OFF_KH);
    float* diag  = (float*)(wsb + OFF_DIAG);
    float* scale = diag + T_ROWS;
    float* s     = scale + T_ROWS;
    float* red   = s + T_ROWS;

    int wid  = threadIdx.x >> 6;
    int lane = threadIdx.x & 63;
    int t = blockIdx.x * 4 + wid;
    int b = t >> 10;
    int n = t & 1023;
    float qv = outE[(size_t)(b * NN + n) * DD + lane];
    float kv = tgtE[(size_t)(b * NN + n + 1) * DD + lane];
    float qs = qv * qv, ks = kv * kv;
    #pragma unroll
    for (int m = 32; m; m >>= 1) {
        qs += __shfl_xor(qs, m, 64);
        ks += __shfl_xor(ks, m, 64);
    }
    float qn  = qv * (1.0f / fmaxf(sqrtf(qs), 1e-12f));
    float knv = kv * (1.0f / fmaxf(sqrtf(ks), 1e-12f));
    qh[(size_t)t * DD + lane] = (_Float16)(qn * C_EXP);
    kh[(size_t)t * DD + lane] = (_Float16)knv;
    float dt = qn * knv;
    #pragma unroll
    for (int m = 32; m; m >>= 1) dt += __shfl_xor(dt, m, 64);
    if (lane == 0) {
        diag[t]  = 20.0f * dt;
        scale[t] = mask[b * NN + n + 1] ? EXP_NEG20 : 0.0f;
        s[t]     = 0.0f;
    }
    if (t == 0 && lane < 2) red[lane] = 0.0f;
}

// ---------------------------------------------------------------------------
// Main: s[i] += sum_j exp2(dot_scaled_ij) * scale_j via f16 MFMA.
// Block = 4 waves; wave owns a 64-row i-strip (4 MFMA row-tiles, Q frags in
// regs); loops 16 j-tiles of 16 cols. No LDS. Fragment layout (m89-verified
// 16x16x32): A lane l -> row=l&15, k=(l>>4)*8.. ; C lane l -> col=l&15,
// row=(l>>4)*4+reg.
// ---------------------------------------------------------------------------
#define JTILES 16
#define JSPAN  256   // cols per block

__global__ __launch_bounds__(256) void logits_kernel(char* __restrict__ wsb)
{
    const _Float16* qh = (const _Float16*)(wsb + OFF_QH);
    const _Float16* kh = (const _Float16*)(wsb + OFF_KH);
    const float* diag_ = (const float*)(wsb + OFF_DIAG);
    const float* scale = diag_ + T_ROWS;
    float* s = (float*)(wsb + OFF_DIAG) + 2 * T_ROWS;

    int ib = blockIdx.x >> 5;   // 32 i-blocks of 256 rows
    int jc = blockIdx.x & 31;   // 32 j-chunks of 256 cols
    int wid  = threadIdx.x >> 6;
    int lane = threadIdx.x & 63;
    int i0 = ib * 256 + wid * 64;
    int r16 = lane & 15;        // A-row / B-col within tile
    int ko  = (lane >> 4) * 8;  // k offset within K=32 chunk

    h8 qf[4][2];
    #pragma unroll
    for (int m = 0; m < 4; ++m)
        #pragma unroll
        for (int kk = 0; kk < 2; ++kk)
            qf[m][kk] = *(const h8*)(qh + (size_t)(i0 + m * 16 + r16) * DD + kk * 32 + ko);

    float acc[4][4];
    #pragma unroll
    for (int m = 0; m < 4; ++m)
        #pragma unroll
        for (int r = 0; r < 4; ++r) acc[m][r] = 0.0f;

    int j0 = jc * JSPAN;
    #pragma unroll 2
    for (int jt = 0; jt < JTILES; ++jt, j0 += 16) {
        float sc = scale[j0 + r16];
        const _Float16* kr = kh + (size_t)(j0 + r16) * DD + ko;
        h8 kf0 = *(const h8*)(kr);
        h8 kf1 = *(const h8*)(kr + 32);
        #pragma unroll
        for (int m = 0; m < 4; ++m) {
            f4 c = {0.f, 0.f, 0.f, 0.f};
            c = __builtin_amdgcn_mfma_f32_16x16x32_f16(qf[m][0], kf0, c, 0, 0, 0);
            c = __builtin_amdgcn_mfma_f32_16x16x32_f16(qf[m][1], kf1, c, 0, 0, 0);
            #pragma unroll
            for (int r = 0; r < 4; ++r)
                acc[m][r] += __builtin_amdgcn_exp2f(c[r]) * sc;
        }
    }

    // Reduce across the 16 col-lanes (same output row)
    #pragma unroll
    for (int msk = 1; msk < 16; msk <<= 1)
        #pragma unroll
        for (int m = 0; m < 4; ++m)
            #pragma unroll
            for (int r = 0; r < 4; ++r)
                acc[m][r] += __shfl_xor(acc[m][r], msk, 64);

    if (r16 == 0) {
        int rbase = i0 + (lane >> 4) * 4;
        #pragma unroll
        for (int m = 0; m < 4; ++m)
            #pragma unroll
            for (int r = 0; r < 4; ++r)
                atomicAdd(&s[rbase + m * 16 + r], acc[m][r]);
    }
}

// ---------------------------------------------------------------------------
// Loss: per-row term, 32-block partial reduce -> atomics, then tiny final.
// ---------------------------------------------------------------------------
__global__ __launch_bounds__(256) void loss_partial(char* __restrict__ wsb)
{
    const float* diag  = (const float*)(wsb + OFF_DIAG);
    const float* scale = diag + T_ROWS;
    const float* s     = scale + T_ROWS;
    float* red         = (float*)(s + T_ROWS);

    int t = blockIdx.x * 256 + threadIdx.x;
    float num = 0.f, den = 0.f;
    if (scale[t] != 0.0f) {
        num = diag[t] - 20.0f - logf(s[t]);
        den = 1.0f;
    }
    #pragma unroll
    for (int m = 32; m; m >>= 1) {
        num += __shfl_xor(num, m, 64);
        den += __shfl_xor(den, m, 64);
    }
    __shared__ float sn[4], sd[4];
    int wid = threadIdx.x >> 6, lane = threadIdx.x & 63;
    if (lane == 0) { sn[wid] = num; sd[wid] = den; }
    __syncthreads();
    if (threadIdx.x == 0) {
        atomicAdd(&red[0], sn[0] + sn[1] + sn[2] + sn[3]);
        atomicAdd(&red[1], sd[0] + sd[1] + sd[2] + sd[3]);
    }
}

__global__ void loss_final(const char* __restrict__ wsb, float* __restrict__ out)
{
    const float* red = (const float*)(wsb + OFF_DIAG) + 3 * T_ROWS;
    out[0] = -red[0] / red[1];
}

extern "C" void kernel_launch(void* const* d_in, const int* in_sizes, int n_in,
                              void* d_out, int out_size, void* d_ws, size_t ws_size,
                              hipStream_t stream) {
    const float* outE = (const float*)d_in[0];
    const float* tgtE = (const float*)d_in[1];
    const int*   mask = (const int*)d_in[2];
    char* wsb = (char*)d_ws;
    float* out = (float*)d_out;

    prep_kernel<<<T_ROWS / 4, 256, 0, stream>>>(outE, tgtE, mask, wsb);
    logits_kernel<<<32 * 32, 256, 0, stream>>>(wsb);
    loss_partial<<<T_ROWS / 256, 256, 0, stream>>>(wsb);
    loss_final<<<1, 1, 0, stream>>>(wsb, out);
}